// Round 16
// baseline (175.237 us; speedup 1.0000x reference)
//
#include <hip/hip_runtime.h>
#include <hip/hip_bf16.h>
#include <math.h>

// Problem constants
constexpr int BB   = 2;
constexpr int SS   = 1024;
constexpr int HID  = 2048;
constexpr int NH   = 32;
constexpr int NKV  = 8;
constexpr int HD   = 64;
constexpr int M    = BB * SS;          // 2048 rows
constexpr int NQKV = 3072;             // fused q|k|v output width

typedef __attribute__((ext_vector_type(8))) short bf8v;   // 8 bf16
typedef __attribute__((ext_vector_type(4))) float f4v;    // 4 f32 acc

static __device__ __forceinline__ unsigned short f2b(float x) {
  __hip_bfloat16 h = __float2bfloat16(x);
  return *reinterpret_cast<unsigned short*>(&h);
}
static __device__ __forceinline__ void gload16(void* lds, const void* g) {
  __builtin_amdgcn_global_load_lds(
      (const __attribute__((address_space(1))) void*)g,
      (__attribute__((address_space(3))) void*)lds, 16, 0, 0);
}

// ---------------------------------------------------------------------------
// Fused prep (one launch, grid 32x32x6):
//  z=0..3: weight transpose+cast (Wq|Wk|Wv -> WqkvT rows, Wo -> WoT)
//  z=4   : RoPE cos/sin table  tab[m][j] (float2), j = 0..31
//  z=5   : castX hidden f32 -> bf16
// ---------------------------------------------------------------------------
__global__ __launch_bounds__(256) void prepAll(
    const float* __restrict__ Wq, const float* __restrict__ Wk,
    const float* __restrict__ Wv, const float* __restrict__ Wo,
    const float* __restrict__ hidden, const int* __restrict__ pos_ids,
    unsigned short* __restrict__ WqkvT, unsigned short* __restrict__ WoT,
    unsigned short* __restrict__ Xb, float2* __restrict__ tab) {
  const int z = blockIdx.z;
  const int t = threadIdx.x;

  if (z == 4) {            // RoPE table
    const int idx = blockIdx.y * 32 + blockIdx.x;
    if ((t & 127) < 32) {
      const int m = idx * 2 + (t >> 7);
      const int j = t & 31;
      const float pos = (float)pos_ids[m];
      const float ang = pos * exp2f(-(float)j * (13.287712379549449f / 32.0f));
      float sn, cs;
      sincosf(ang, &sn, &cs);
      tab[(size_t)m * 32 + j] = make_float2(cs, sn);
    }
    return;
  }
  if (z == 5) {            // castX
    const size_t base = ((size_t)(blockIdx.y * 32 + blockIdx.x)) * 4096;
#pragma unroll
    for (int it = 0; it < 2; ++it) {
      const size_t i = base + it * 2048 + t * 8;
      const float4 v0 = *(const float4*)(hidden + i);
      const float4 v1 = *(const float4*)(hidden + i + 4);
      unsigned short o[8] = {f2b(v0.x), f2b(v0.y), f2b(v0.z), f2b(v0.w),
                             f2b(v1.x), f2b(v1.y), f2b(v1.z), f2b(v1.w)};
      *(bf8v*)(Xb + i) = *(bf8v*)o;
    }
    return;
  }

  const float* src;
  unsigned short* dst;
  int C;
  if (z == 0)      { src = Wq; dst = WqkvT;                      C = 2048; }
  else if (z == 1) { src = Wk; dst = WqkvT + (size_t)2048 * HID; C = 512;  }
  else if (z == 2) { src = Wv; dst = WqkvT + (size_t)2560 * HID; C = 512;  }
  else             { src = Wo; dst = WoT;                        C = 2048; }

  const int r0 = blockIdx.y * 64, c0 = blockIdx.x * 64;
  if (c0 >= C) return;
  __shared__ float T[64][65];
  {
    const int r  = t >> 2;
    const int c4 = (t & 3) * 16;
    const float* sp = src + (size_t)(r0 + r) * C + c0 + c4;
    *(float4*)&T[r][c4 + 0]  = *(const float4*)(sp + 0);
    *(float4*)&T[r][c4 + 4]  = *(const float4*)(sp + 4);
    *(float4*)&T[r][c4 + 8]  = *(const float4*)(sp + 8);
    *(float4*)&T[r][c4 + 12] = *(const float4*)(sp + 12);
  }
  __syncthreads();
  {
    const int c  = t >> 2;
    const int rr = (t & 3) * 16;
    unsigned short o[16];
#pragma unroll
    for (int i = 0; i < 16; ++i) o[i] = f2b(T[rr + i][c]);
    unsigned short* dp = dst + (size_t)(c0 + c) * HID + r0 + rr;
    *(bf8v*)dp       = *(bf8v*)&o[0];
    *(bf8v*)(dp + 8) = *(bf8v*)&o[8];
  }
}

// ===========================================================================
// GEMM core notes (both gemm_qkv and gemm_bf16):
//  * 128x128 tile, 4 waves 2x2, BK=32, 64 K-steps.
//  * T4: 3-buffer staging, counted vmcnt. stage(t+2) issued in step t; the
//    end-of-step barrier waits only vmcnt(4) (per-wave: 4 loads of buf t+1
//    landed; buf t+2's 4 stay in flight). Load latency hidden across 2 steps.
//    Raw s_barrier (no compiler vmcnt(0) drain).
//  * T2: 16B-slot XOR swizzle, both sides (rule #21): physical slot
//    p = lg ^ ((row>>1)&3). Write side: global source column pre-swizzled
//    (LDS dest stays linear for global_load_lds). Read side: same XOR on
//    ds_read address. 8-way bank conflict -> 2-way (free).
// ===========================================================================

// ---------------------------------------------------------------------------
// QKV GEMM with fused RoPE epilogue.
// ---------------------------------------------------------------------------
__global__ __launch_bounds__(256) void gemm_qkv(
    const unsigned short* __restrict__ A, const unsigned short* __restrict__ Bt,
    const float2* __restrict__ tab,
    unsigned short* __restrict__ Qb, unsigned short* __restrict__ Kb,
    unsigned short* __restrict__ Vb) {
  __shared__ unsigned short As[3][128 * 32];
  __shared__ unsigned short Bs[3][128 * 32];
  const int Kdim = HID;
  const int t  = threadIdx.x;
  const int w  = t >> 6, l = t & 63;
  const int lr = l & 15, lg = l >> 4;
  const int wr = w >> 1, wc = w & 1;
  const int bm = blockIdx.y * 128, bn = blockIdx.x * 128;

  f4v acc[4][4] = {};

  const unsigned short* Ablk = A  + (size_t)bm * Kdim;
  const unsigned short* Bblk = Bt + (size_t)bn * Kdim;
  const int srow = l >> 2;                          // staged row within 16
  const int scol = (((l & 3) ^ ((srow >> 1) & 3)) * 8);  // swizzled src col
  const int rsl  = (lg ^ ((lr >> 1) & 3)) * 8;      // swizzled read slot

  auto stage = [&](int buf, int k0) {
    gload16(&As[buf][(w * 32)      * 32], Ablk + (size_t)(w * 32 +      srow) * Kdim + k0 + scol);
    gload16(&As[buf][(w * 32 + 16) * 32], Ablk + (size_t)(w * 32 + 16 + srow) * Kdim + k0 + scol);
    gload16(&Bs[buf][(w * 32)      * 32], Bblk + (size_t)(w * 32 +      srow) * Kdim + k0 + scol);
    gload16(&Bs[buf][(w * 32 + 16) * 32], Bblk + (size_t)(w * 32 + 16 + srow) * Kdim + k0 + scol);
  };

  const int nsteps = Kdim / 32;          // 64
  stage(0, 0);
  stage(1, 32);
  asm volatile("s_waitcnt vmcnt(4)" ::: "memory");   // buf0 ready
  __builtin_amdgcn_s_barrier();

  int cur = 0;
  const int aoff = (wr * 64 + lr) * 32 + rsl;
  const int boff = (wc * 64 + lr) * 32 + rsl;
  for (int tt = 0; tt < nsteps; ++tt) {
    if (tt + 2 < nsteps) stage((tt + 2) % 3, (tt + 2) * 32);

    bf8v aF[4], bF[4];
#pragma unroll
    for (int i = 0; i < 4; ++i) {
      aF[i] = *(const bf8v*)&As[cur][aoff + i * 512];
      bF[i] = *(const bf8v*)&Bs[cur][boff + i * 512];
    }
    __builtin_amdgcn_s_setprio(1);
#pragma unroll
    for (int mi = 0; mi < 4; ++mi)
#pragma unroll
      for (int ni = 0; ni < 4; ++ni)
        acc[mi][ni] = __builtin_amdgcn_mfma_f32_16x16x32_bf16(aF[mi], bF[ni], acc[mi][ni], 0, 0, 0);
    __builtin_amdgcn_s_setprio(0);

    if (tt + 2 < nsteps) { asm volatile("s_waitcnt vmcnt(4)" ::: "memory"); }
    else                 { asm volatile("s_waitcnt vmcnt(0)" ::: "memory"); }
    __builtin_amdgcn_s_barrier();
    cur = (cur + 1) % 3;
  }

  // Fused RoPE epilogue. D layout: row = lg*4+r, col = lr (m89/m91).
  const int row0 = bm + wr * 64;
  const int colHead = bn + wc * 64;          // this wave's head start col
  unsigned short* outArr;
  int hh, headsPerB, mode;                   // 0=Q(rope+scale) 1=K(rope) 2=V
  if (colHead < 2048)      { mode = 0; outArr = Qb; hh = colHead >> 6;          headsPerB = NH;  }
  else if (colHead < 2560) { mode = 1; outArr = Kb; hh = (colHead - 2048) >> 6; headsPerB = NKV; }
  else                     { mode = 2; outArr = Vb; hh = (colHead - 2560) >> 6; headsPerB = NKV; }

#pragma unroll
  for (int mi = 0; mi < 4; ++mi)
#pragma unroll
    for (int r = 0; r < 4; ++r) {
      const int rowg = row0 + mi * 16 + lg * 4 + r;
      const int bI = rowg >> 10, s = rowg & (SS - 1);
      unsigned short* dst =
          outArr + ((size_t)(bI * headsPerB + hh) * SS + s) * 64;
      if (mode == 2) {
#pragma unroll
        for (int ni = 0; ni < 4; ++ni)
          dst[ni * 16 + lr] = f2b(acc[mi][ni][r]);
      } else {
        const float2 cs_lo = tab[(size_t)rowg * 32 + lr];
        const float2 cs_hi = tab[(size_t)rowg * 32 + 16 + lr];
#pragma unroll
        for (int ni = 0; ni < 4; ++ni) {
          const float2 cs = (ni & 1) ? cs_hi : cs_lo;
          const float x   = acc[mi][ni][r];
          const float prt = acc[mi][ni ^ 2][r];
          const float rh  = (ni < 2) ? -prt : prt;
          float v = x * cs.x + rh * cs.y;
          if (mode == 0) v *= 0.125f;
          dst[ni * 16 + lr] = f2b(v);
        }
      }
    }
}

// ---------------------------------------------------------------------------
// Plain bf16 GEMM for Wo (same T4+T2 core), f32 out.
// ---------------------------------------------------------------------------
__global__ __launch_bounds__(256) void gemm_bf16(
    const unsigned short* __restrict__ A, const unsigned short* __restrict__ Bt,
    float* __restrict__ C, int Ndim, int Kdim) {
  __shared__ unsigned short As[3][128 * 32];
  __shared__ unsigned short Bs[3][128 * 32];
  const int t  = threadIdx.x;
  const int w  = t >> 6, l = t & 63;
  const int lr = l & 15, lg = l >> 4;
  const int wr = w >> 1, wc = w & 1;
  const int bm = blockIdx.y * 128, bn = blockIdx.x * 128;

  f4v acc[4][4] = {};

  const unsigned short* Ablk = A  + (size_t)bm * Kdim;
  const unsigned short* Bblk = Bt + (size_t)bn * Kdim;
  const int srow = l >> 2;
  const int scol = (((l & 3) ^ ((srow >> 1) & 3)) * 8);
  const int rsl  = (lg ^ ((lr >> 1) & 3)) * 8;

  auto stage = [&](int buf, int k0) {
    gload16(&As[buf][(w * 32)      * 32], Ablk + (size_t)(w * 32 +      srow) * Kdim + k0 + scol);
    gload16(&As[buf][(w * 32 + 16) * 32], Ablk + (size_t)(w * 32 + 16 + srow) * Kdim + k0 + scol);
    gload16(&Bs[buf][(w * 32)      * 32], Bblk + (size_t)(w * 32 +      srow) * Kdim + k0 + scol);
    gload16(&Bs[buf][(w * 32 + 16) * 32], Bblk + (size_t)(w * 32 + 16 + srow) * Kdim + k0 + scol);
  };

  const int nsteps = Kdim / 32;
  stage(0, 0);
  stage(1, 32);
  asm volatile("s_waitcnt vmcnt(4)" ::: "memory");
  __builtin_amdgcn_s_barrier();

  int cur = 0;
  const int aoff = (wr * 64 + lr) * 32 + rsl;
  const int boff = (wc * 64 + lr) * 32 + rsl;
  for (int tt = 0; tt < nsteps; ++tt) {
    if (tt + 2 < nsteps) stage((tt + 2) % 3, (tt + 2) * 32);

    bf8v aF[4], bF[4];
#pragma unroll
    for (int i = 0; i < 4; ++i) {
      aF[i] = *(const bf8v*)&As[cur][aoff + i * 512];
      bF[i] = *(const bf8v*)&Bs[cur][boff + i * 512];
    }
    __builtin_amdgcn_s_setprio(1);
#pragma unroll
    for (int mi = 0; mi < 4; ++mi)
#pragma unroll
      for (int ni = 0; ni < 4; ++ni)
        acc[mi][ni] = __builtin_amdgcn_mfma_f32_16x16x32_bf16(aF[mi], bF[ni], acc[mi][ni], 0, 0, 0);
    __builtin_amdgcn_s_setprio(0);

    if (tt + 2 < nsteps) { asm volatile("s_waitcnt vmcnt(4)" ::: "memory"); }
    else                 { asm volatile("s_waitcnt vmcnt(0)" ::: "memory"); }
    __builtin_amdgcn_s_barrier();
    cur = (cur + 1) % 3;
  }

  const int row0 = bm + wr * 64;
  const int col0 = bn + wc * 64;
#pragma unroll
  for (int mi = 0; mi < 4; ++mi)
#pragma unroll
    for (int r = 0; r < 4; ++r) {
      const size_t rowoff = (size_t)(row0 + mi * 16 + lg * 4 + r) * Ndim;
#pragma unroll
      for (int ni = 0; ni < 4; ++ni)
        C[rowoff + col0 + ni * 16 + lr] = acc[mi][ni][r];
    }
}

// ---------------------------------------------------------------------------
// V transpose: Vb [bkv][s][64] -> Vt [bkv][64][S]   (bf16)
// ---------------------------------------------------------------------------
__global__ __launch_bounds__(256) void vtrans(
    const unsigned short* __restrict__ Vb, unsigned short* __restrict__ Vt) {
  const int bkv = blockIdx.y;
  const int s0  = blockIdx.x * 64;
  __shared__ unsigned short T[64][72];
  const int t = threadIdx.x;
  const unsigned short* src = Vb + ((size_t)bkv * SS + s0) * 64;
  {
    const int r  = t >> 2;
    const int co = (t & 3) * 16;
    *(bf8v*)&T[r][co]     = *(const bf8v*)(src + (size_t)r * 64 + co);
    *(bf8v*)&T[r][co + 8] = *(const bf8v*)(src + (size_t)r * 64 + co + 8);
  }
  __syncthreads();
  {
    const int d  = t >> 2;
    const int so = (t & 3) * 16;
    unsigned short tmp[16];
#pragma unroll
    for (int i = 0; i < 16; ++i) tmp[i] = T[so + i][d];
    unsigned short* dst = Vt + ((size_t)(bkv * 64 + d)) * SS + s0 + so;
    *(bf8v*)dst       = *(bf8v*)&tmp[0];
    *(bf8v*)(dst + 8) = *(bf8v*)&tmp[8];
  }
}

// ---------------------------------------------------------------------------
// Flash attention (round-11 structure, best measured ~53us).
// ---------------------------------------------------------------------------
__global__ __launch_bounds__(128) void attn_mfma(
    const unsigned short* __restrict__ Qb, const unsigned short* __restrict__ Kb,
    const unsigned short* __restrict__ Vt, unsigned short* __restrict__ attn) {
  const int xb = blockIdx.x;
  const int h = blockIdx.y, b = blockIdx.z;
  const int kv = h >> 2;
  const int w  = threadIdx.x >> 6;
  const int l  = threadIdx.x & 63;
  const int lr = l & 15;
  const int lg = l >> 4;
  const int t  = threadIdx.x;

  __shared__ unsigned short VT[64][72];
  __shared__ unsigned short PL[2][16][72];

  const unsigned short* Kp = Kb + ((size_t)((b * NKV + kv) * SS)) * 64;
  const unsigned short* Vp = Vt + ((size_t)((b * NKV + kv) * 64)) * SS;

  const int vd  = t >> 1;
  const int vso = (t & 1) * 32;

  for (int half = 0; half < 2; ++half) {
    const int qt = half ? (31 - xb) : xb;
    const int qbase = qt * 32;
    const int qW = qbase + w * 16;
    const unsigned short* Qp = Qb + ((size_t)((b * NH + h) * SS + qW)) * 64;
    bf8v aQ0 = *(const bf8v*)(Qp + (size_t)lr * 64 + lg * 8);
    bf8v aQ1 = *(const bf8v*)(Qp + (size_t)lr * 64 + 32 + lg * 8);

    f4v o[4] = {{0,0,0,0},{0,0,0,0},{0,0,0,0},{0,0,0,0}};
    float lsumL[4] = {0.f, 0.f, 0.f, 0.f};

    for (int kvb = 0; kvb < qbase + 32; kvb += 64) {
      __syncthreads();
      const unsigned short* vp = Vp + (size_t)vd * SS + kvb + vso;
      const bf8v v0 = *(const bf8v*)(vp);
      const bf8v v1 = *(const bf8v*)(vp + 8);
      const bf8v v2 = *(const bf8v*)(vp + 16);
      const bf8v v3 = *(const bf8v*)(vp + 24);

      f4v sc[4] = {{0,0,0,0},{0,0,0,0},{0,0,0,0},{0,0,0,0}};
      __builtin_amdgcn_s_setprio(1);
#pragma unroll
      for (int c = 0; c < 4; ++c) {
        const unsigned short* kr = Kp + (size_t)(kvb + c * 16 + lr) * 64 + lg * 8;
        bf8v b0 = *(const bf8v*)(kr);
        bf8v b1 = *(const bf8v*)(kr + 32);
        sc[c] = __builtin_amdgcn_mfma_f32_16x16x32_bf16(aQ0, b0, sc[c], 0, 0, 0);
        sc[c] = __builtin_amdgcn_mfma_f32_16x16x32_bf16(aQ1, b1, sc[c], 0, 0, 0);
      }
      __builtin_amdgcn_s_setprio(0);

#pragma unroll
      for (int r = 0; r < 4; ++r) {
        const int qrow = qW + lg * 4 + r;
        float ps = 0.f;
        unsigned short pb[4];
#pragma unroll
        for (int c = 0; c < 4; ++c) {
          const float s = ((kvb + c * 16 + lr) > qrow) ? -INFINITY : sc[c][r];
          const float p = __expf(s);
          ps += p;
          pb[c] = f2b(p);
        }
        lsumL[r] += ps;
#pragma unroll
        for (int c = 0; c < 4; ++c) PL[w][lg * 4 + r][c * 16 + lr] = pb[c];
      }

      *(bf8v*)&VT[vd][vso]      = v0;
      *(bf8v*)&VT[vd][vso + 8]  = v1;
      *(bf8v*)&VT[vd][vso + 16] = v2;
      *(bf8v*)&VT[vd][vso + 24] = v3;

      __syncthreads();

      bf8v aP0 = *(const bf8v*)&PL[w][lr][lg * 8];
      bf8v aP1 = *(const bf8v*)&PL[w][lr][32 + lg * 8];
      __builtin_amdgcn_s_setprio(1);
#pragma unroll
      for (int n = 0; n < 4; ++n) {
        bf8v bV0 = *(const bf8v*)&VT[n * 16 + lr][lg * 8];
        bf8v bV1 = *(const bf8v*)&VT[n * 16 + lr][32 + lg * 8];
        o[n] = __builtin_amdgcn_mfma_f32_16x16x32_bf16(aP0, bV0, o[n], 0, 0, 0);
        o[n] = __builtin_amdgcn_mfma_f32_16x16x32_bf16(aP1, bV1, o[n], 0, 0, 0);
      }
      __builtin_amdgcn_s_setprio(0);
    }

#pragma unroll
    for (int r = 0; r < 4; ++r) {
      float ls = lsumL[r];
      ls += __shfl_xor(ls, 1);
      ls += __shfl_xor(ls, 2);
      ls += __shfl_xor(ls, 4);
      ls += __shfl_xor(ls, 8);
      const float inv = 1.0f / ls;
      const int row = qW + lg * 4 + r;
      unsigned short* dst = attn + (size_t)(b * SS + row) * HID + h * 64;
#pragma unroll
      for (int n = 0; n < 4; ++n) dst[n * 16 + lr] = f2b(o[n][r] * inv);
    }
  }
}

// ---------------------------------------------------------------------------
extern "C" void kernel_launch(void* const* d_in, const int* in_sizes, int n_in,
                              void* d_out, int out_size, void* d_ws, size_t ws_size,
                              hipStream_t stream) {
  const float* hidden = (const float*)d_in[0];
  const int*   pos    = (const int*)d_in[1];
  const float* Wq = (const float*)d_in[3];
  const float* Wk = (const float*)d_in[4];
  const float* Wv = (const float*)d_in[5];
  const float* Wo = (const float*)d_in[6];
  float* out = (float*)d_out;

  char* ws = (char*)d_ws;
  unsigned short* WqkvT = (unsigned short*)(ws);              // 12 MB  [3072][2048]
  unsigned short* WoT   = (unsigned short*)(ws + 12582912);   //  8 MB  [2048][2048]
  unsigned short* Xb    = (unsigned short*)(ws + 20971520);   //  8 MB  [M][2048]
  unsigned short* attnb = Xb;                                 // alias (Xb dead after gemm_qkv)
  unsigned short* Qb    = (unsigned short*)(ws + 29360128);   //  8 MB  [B][NH][S][64]
  unsigned short* Kb    = (unsigned short*)(ws + 37748736);   //  2 MB  [B][NKV][S][64]
  unsigned short* Vb    = (unsigned short*)(ws + 39845888);   //  2 MB  [B][NKV][S][64]
  unsigned short* Vt    = (unsigned short*)(ws + 41943040);   //  2 MB  [B*NKV][64][S]
  float2*         tab   = (float2*)(ws + 44040192);           // 512 KB [M][32]

  dim3 blk(256);

  prepAll<<<dim3(32, 32, 6), blk, 0, stream>>>(Wq, Wk, Wv, Wo, hidden, pos,
                                               WqkvT, WoT, Xb, tab);

  gemm_qkv<<<dim3(NQKV / 128, M / 128), blk, 0, stream>>>(Xb, WqkvT, tab, Qb, Kb, Vb);

  vtrans<<<dim3(SS / 64, BB * NKV), blk, 0, stream>>>(Vb, Vt);

  attn_mfma<<<dim3(16, NH, BB), dim3(128), 0, stream>>>(Qb, Kb, Vt, attnb);

  gemm_bf16<<<dim3(HID / 128, M / 128), blk, 0, stream>>>(attnb, WoT, out, HID, HID);
}

// Round 17
// 156.530 us; speedup vs baseline: 1.1195x; 1.1195x over previous
//
#include <hip/hip_runtime.h>
#include <hip/hip_bf16.h>
#include <math.h>

// Problem constants
constexpr int BB   = 2;
constexpr int SS   = 1024;
constexpr int HID  = 2048;
constexpr int NH   = 32;
constexpr int NKV  = 8;
constexpr int HD   = 64;
constexpr int M    = BB * SS;          // 2048 rows
constexpr int NQKV = 3072;             // fused q|k|v output width

typedef __attribute__((ext_vector_type(8))) short bf8v;   // 8 bf16
typedef __attribute__((ext_vector_type(4))) float f4v;    // 4 f32 acc

static __device__ __forceinline__ unsigned short f2b(float x) {
  __hip_bfloat16 h = __float2bfloat16(x);
  return *reinterpret_cast<unsigned short*>(&h);
}
static __device__ __forceinline__ void gload16(void* lds, const void* g) {
  __builtin_amdgcn_global_load_lds(
      (const __attribute__((address_space(1))) void*)g,
      (__attribute__((address_space(3))) void*)lds, 16, 0, 0);
}

// ---------------------------------------------------------------------------
// Fused prep (one launch, grid 32x32x6): weight transposes, RoPE table, castX
// ---------------------------------------------------------------------------
__global__ __launch_bounds__(256) void prepAll(
    const float* __restrict__ Wq, const float* __restrict__ Wk,
    const float* __restrict__ Wv, const float* __restrict__ Wo,
    const float* __restrict__ hidden, const int* __restrict__ pos_ids,
    unsigned short* __restrict__ WqkvT, unsigned short* __restrict__ WoT,
    unsigned short* __restrict__ Xb, float2* __restrict__ tab) {
  const int z = blockIdx.z;
  const int t = threadIdx.x;

  if (z == 4) {            // RoPE table
    const int idx = blockIdx.y * 32 + blockIdx.x;
    if ((t & 127) < 32) {
      const int m = idx * 2 + (t >> 7);
      const int j = t & 31;
      const float pos = (float)pos_ids[m];
      const float ang = pos * exp2f(-(float)j * (13.287712379549449f / 32.0f));
      float sn, cs;
      sincosf(ang, &sn, &cs);
      tab[(size_t)m * 32 + j] = make_float2(cs, sn);
    }
    return;
  }
  if (z == 5) {            // castX
    const size_t base = ((size_t)(blockIdx.y * 32 + blockIdx.x)) * 4096;
#pragma unroll
    for (int it = 0; it < 2; ++it) {
      const size_t i = base + it * 2048 + t * 8;
      const float4 v0 = *(const float4*)(hidden + i);
      const float4 v1 = *(const float4*)(hidden + i + 4);
      unsigned short o[8] = {f2b(v0.x), f2b(v0.y), f2b(v0.z), f2b(v0.w),
                             f2b(v1.x), f2b(v1.y), f2b(v1.z), f2b(v1.w)};
      *(bf8v*)(Xb + i) = *(bf8v*)o;
    }
    return;
  }

  const float* src;
  unsigned short* dst;
  int C;
  if (z == 0)      { src = Wq; dst = WqkvT;                      C = 2048; }
  else if (z == 1) { src = Wk; dst = WqkvT + (size_t)2048 * HID; C = 512;  }
  else if (z == 2) { src = Wv; dst = WqkvT + (size_t)2560 * HID; C = 512;  }
  else             { src = Wo; dst = WoT;                        C = 2048; }

  const int r0 = blockIdx.y * 64, c0 = blockIdx.x * 64;
  if (c0 >= C) return;
  __shared__ float T[64][65];
  {
    const int r  = t >> 2;
    const int c4 = (t & 3) * 16;
    const float* sp = src + (size_t)(r0 + r) * C + c0 + c4;
    *(float4*)&T[r][c4 + 0]  = *(const float4*)(sp + 0);
    *(float4*)&T[r][c4 + 4]  = *(const float4*)(sp + 4);
    *(float4*)&T[r][c4 + 8]  = *(const float4*)(sp + 8);
    *(float4*)&T[r][c4 + 12] = *(const float4*)(sp + 12);
  }
  __syncthreads();
  {
    const int c  = t >> 2;
    const int rr = (t & 3) * 16;
    unsigned short o[16];
#pragma unroll
    for (int i = 0; i < 16; ++i) o[i] = f2b(T[rr + i][c]);
    unsigned short* dp = dst + (size_t)(c0 + c) * HID + r0 + rr;
    *(bf8v*)dp       = *(bf8v*)&o[0];
    *(bf8v*)(dp + 8) = *(bf8v*)&o[8];
  }
}

// ===========================================================================
// GEMM core (both kernels): 64x128 tile, 4 waves 2x2 (each wave 32x64),
// BK=32, K=2048 (64 steps).
//  * Balanced grids: QKV 768 blocks = 3/CU exact; Wo 512 = 2/CU exact.
//  * T4 depth-3: 4 LDS buffers (48KB -> 3 blocks/CU), stage(t+3) issued in
//    step t, wait vmcnt(6) => buffer t+1 landed while t+2,t+3 stay in
//    flight across the raw barrier. Tail counts 6/3/0.
//  * T2 16B-slot XOR swizzle both sides (proven conflict-free, round 16).
//  * Per-wave staging: 1 A-gload16 (16 rows) + 2 B-gload16 (32 rows) = 3.
// ===========================================================================

// ---------------------------------------------------------------------------
// QKV GEMM with fused RoPE epilogue.
// ---------------------------------------------------------------------------
__global__ __launch_bounds__(256) void gemm_qkv(
    const unsigned short* __restrict__ A, const unsigned short* __restrict__ Bt,
    const float2* __restrict__ tab,
    unsigned short* __restrict__ Qb, unsigned short* __restrict__ Kb,
    unsigned short* __restrict__ Vb) {
  __shared__ unsigned short As[4][64 * 32];
  __shared__ unsigned short Bs[4][128 * 32];
  const int t  = threadIdx.x;
  const int w  = t >> 6, l = t & 63;
  const int lr = l & 15, lg = l >> 4;
  const int wr = w >> 1, wc = w & 1;
  const int bm = blockIdx.y * 64, bn = blockIdx.x * 128;

  f4v acc[2][4] = {};

  const unsigned short* Ablk = A  + (size_t)bm * HID;
  const unsigned short* Bblk = Bt + (size_t)bn * HID;
  const int srow = l >> 2;
  const int scol = (((l & 3) ^ ((srow >> 1) & 3)) * 8);
  const int rsl  = (lg ^ ((lr >> 1) & 3)) * 8;

  auto stage = [&](int buf, int k0) {
    gload16(&As[buf][(w * 16) * 32], Ablk + (size_t)(w * 16 + srow) * HID + k0 + scol);
    gload16(&Bs[buf][(w * 32)      * 32], Bblk + (size_t)(w * 32 +      srow) * HID + k0 + scol);
    gload16(&Bs[buf][(w * 32 + 16) * 32], Bblk + (size_t)(w * 32 + 16 + srow) * HID + k0 + scol);
  };

  const int nsteps = HID / 32;           // 64
  stage(0, 0);
  stage(1, 32);
  stage(2, 64);
  asm volatile("s_waitcnt vmcnt(6)" ::: "memory");   // buf0 landed
  __builtin_amdgcn_s_barrier();

  const int aoff = (wr * 32 + lr) * 32 + rsl;
  const int boff = (wc * 64 + lr) * 32 + rsl;
  for (int tt = 0; tt < nsteps; ++tt) {
    const int cur = tt & 3;
    if (tt + 3 < nsteps) stage((tt + 3) & 3, (tt + 3) * 32);

    bf8v aF[2], bF[4];
#pragma unroll
    for (int i = 0; i < 2; ++i)
      aF[i] = *(const bf8v*)&As[cur][aoff + i * 512];
#pragma unroll
    for (int j = 0; j < 4; ++j)
      bF[j] = *(const bf8v*)&Bs[cur][boff + j * 512];
    __builtin_amdgcn_s_setprio(1);
#pragma unroll
    for (int mi = 0; mi < 2; ++mi)
#pragma unroll
      for (int ni = 0; ni < 4; ++ni)
        acc[mi][ni] = __builtin_amdgcn_mfma_f32_16x16x32_bf16(aF[mi], bF[ni], acc[mi][ni], 0, 0, 0);
    __builtin_amdgcn_s_setprio(0);

    if (tt + 3 < nsteps)      { asm volatile("s_waitcnt vmcnt(6)" ::: "memory"); }
    else if (tt + 2 < nsteps) { asm volatile("s_waitcnt vmcnt(3)" ::: "memory"); }
    else                      { asm volatile("s_waitcnt vmcnt(0)" ::: "memory"); }
    __builtin_amdgcn_s_barrier();
  }

  // Fused RoPE epilogue. D layout: row = lg*4+r, col = lr (m89/m91).
  const int row0 = bm + wr * 32;
  const int colHead = bn + wc * 64;
  unsigned short* outArr;
  int hh, headsPerB, mode;                   // 0=Q(rope+scale) 1=K(rope) 2=V
  if (colHead < 2048)      { mode = 0; outArr = Qb; hh = colHead >> 6;          headsPerB = NH;  }
  else if (colHead < 2560) { mode = 1; outArr = Kb; hh = (colHead - 2048) >> 6; headsPerB = NKV; }
  else                     { mode = 2; outArr = Vb; hh = (colHead - 2560) >> 6; headsPerB = NKV; }

#pragma unroll
  for (int mi = 0; mi < 2; ++mi)
#pragma unroll
    for (int r = 0; r < 4; ++r) {
      const int rowg = row0 + mi * 16 + lg * 4 + r;
      const int bI = rowg >> 10, s = rowg & (SS - 1);
      unsigned short* dst =
          outArr + ((size_t)(bI * headsPerB + hh) * SS + s) * 64;
      if (mode == 2) {
#pragma unroll
        for (int ni = 0; ni < 4; ++ni)
          dst[ni * 16 + lr] = f2b(acc[mi][ni][r]);
      } else {
        const float2 cs_lo = tab[(size_t)rowg * 32 + lr];
        const float2 cs_hi = tab[(size_t)rowg * 32 + 16 + lr];
#pragma unroll
        for (int ni = 0; ni < 4; ++ni) {
          const float2 cs = (ni & 1) ? cs_hi : cs_lo;
          const float x   = acc[mi][ni][r];
          const float prt = acc[mi][ni ^ 2][r];
          const float rh  = (ni < 2) ? -prt : prt;
          float v = x * cs.x + rh * cs.y;
          if (mode == 0) v *= 0.125f;
          dst[ni * 16 + lr] = f2b(v);
        }
      }
    }
}

// ---------------------------------------------------------------------------
// Plain bf16 GEMM for Wo (same core), f32 out. K = HID fixed.
// ---------------------------------------------------------------------------
__global__ __launch_bounds__(256) void gemm_bf16(
    const unsigned short* __restrict__ A, const unsigned short* __restrict__ Bt,
    float* __restrict__ C, int Ndim) {
  __shared__ unsigned short As[4][64 * 32];
  __shared__ unsigned short Bs[4][128 * 32];
  const int t  = threadIdx.x;
  const int w  = t >> 6, l = t & 63;
  const int lr = l & 15, lg = l >> 4;
  const int wr = w >> 1, wc = w & 1;
  const int bm = blockIdx.y * 64, bn = blockIdx.x * 128;

  f4v acc[2][4] = {};

  const unsigned short* Ablk = A  + (size_t)bm * HID;
  const unsigned short* Bblk = Bt + (size_t)bn * HID;
  const int srow = l >> 2;
  const int scol = (((l & 3) ^ ((srow >> 1) & 3)) * 8);
  const int rsl  = (lg ^ ((lr >> 1) & 3)) * 8;

  auto stage = [&](int buf, int k0) {
    gload16(&As[buf][(w * 16) * 32], Ablk + (size_t)(w * 16 + srow) * HID + k0 + scol);
    gload16(&Bs[buf][(w * 32)      * 32], Bblk + (size_t)(w * 32 +      srow) * HID + k0 + scol);
    gload16(&Bs[buf][(w * 32 + 16) * 32], Bblk + (size_t)(w * 32 + 16 + srow) * HID + k0 + scol);
  };

  const int nsteps = HID / 32;
  stage(0, 0);
  stage(1, 32);
  stage(2, 64);
  asm volatile("s_waitcnt vmcnt(6)" ::: "memory");
  __builtin_amdgcn_s_barrier();

  const int aoff = (wr * 32 + lr) * 32 + rsl;
  const int boff = (wc * 64 + lr) * 32 + rsl;
  for (int tt = 0; tt < nsteps; ++tt) {
    const int cur = tt & 3;
    if (tt + 3 < nsteps) stage((tt + 3) & 3, (tt + 3) * 32);

    bf8v aF[2], bF[4];
#pragma unroll
    for (int i = 0; i < 2; ++i)
      aF[i] = *(const bf8v*)&As[cur][aoff + i * 512];
#pragma unroll
    for (int j = 0; j < 4; ++j)
      bF[j] = *(const bf8v*)&Bs[cur][boff + j * 512];
    __builtin_amdgcn_s_setprio(1);
#pragma unroll
    for (int mi = 0; mi < 2; ++mi)
#pragma unroll
      for (int ni = 0; ni < 4; ++ni)
        acc[mi][ni] = __builtin_amdgcn_mfma_f32_16x16x32_bf16(aF[mi], bF[ni], acc[mi][ni], 0, 0, 0);
    __builtin_amdgcn_s_setprio(0);

    if (tt + 3 < nsteps)      { asm volatile("s_waitcnt vmcnt(6)" ::: "memory"); }
    else if (tt + 2 < nsteps) { asm volatile("s_waitcnt vmcnt(3)" ::: "memory"); }
    else                      { asm volatile("s_waitcnt vmcnt(0)" ::: "memory"); }
    __builtin_amdgcn_s_barrier();
  }

  const int row0 = bm + wr * 32;
  const int col0 = bn + wc * 64;
#pragma unroll
  for (int mi = 0; mi < 2; ++mi)
#pragma unroll
    for (int r = 0; r < 4; ++r) {
      const size_t rowoff = (size_t)(row0 + mi * 16 + lg * 4 + r) * Ndim;
#pragma unroll
      for (int ni = 0; ni < 4; ++ni)
        C[rowoff + col0 + ni * 16 + lr] = acc[mi][ni][r];
    }
}

// ---------------------------------------------------------------------------
// V transpose: Vb [bkv][s][64] -> Vt [bkv][64][S]   (bf16)
// ---------------------------------------------------------------------------
__global__ __launch_bounds__(256) void vtrans(
    const unsigned short* __restrict__ Vb, unsigned short* __restrict__ Vt) {
  const int bkv = blockIdx.y;
  const int s0  = blockIdx.x * 64;
  __shared__ unsigned short T[64][72];
  const int t = threadIdx.x;
  const unsigned short* src = Vb + ((size_t)bkv * SS + s0) * 64;
  {
    const int r  = t >> 2;
    const int co = (t & 3) * 16;
    *(bf8v*)&T[r][co]     = *(const bf8v*)(src + (size_t)r * 64 + co);
    *(bf8v*)&T[r][co + 8] = *(const bf8v*)(src + (size_t)r * 64 + co + 8);
  }
  __syncthreads();
  {
    const int d  = t >> 2;
    const int so = (t & 3) * 16;
    unsigned short tmp[16];
#pragma unroll
    for (int i = 0; i < 16; ++i) tmp[i] = T[so + i][d];
    unsigned short* dst = Vt + ((size_t)(bkv * 64 + d)) * SS + s0 + so;
    *(bf8v*)dst       = *(bf8v*)&tmp[0];
    *(bf8v*)(dst + 8) = *(bf8v*)&tmp[8];
  }
}

// ---------------------------------------------------------------------------
// Flash attention (round-11 structure, best measured ~53us).
// ---------------------------------------------------------------------------
__global__ __launch_bounds__(128) void attn_mfma(
    const unsigned short* __restrict__ Qb, const unsigned short* __restrict__ Kb,
    const unsigned short* __restrict__ Vt, unsigned short* __restrict__ attn) {
  const int xb = blockIdx.x;
  const int h = blockIdx.y, b = blockIdx.z;
  const int kv = h >> 2;
  const int w  = threadIdx.x >> 6;
  const int l  = threadIdx.x & 63;
  const int lr = l & 15;
  const int lg = l >> 4;
  const int t  = threadIdx.x;

  __shared__ unsigned short VT[64][72];
  __shared__ unsigned short PL[2][16][72];

  const unsigned short* Kp = Kb + ((size_t)((b * NKV + kv) * SS)) * 64;
  const unsigned short* Vp = Vt + ((size_t)((b * NKV + kv) * 64)) * SS;

  const int vd  = t >> 1;
  const int vso = (t & 1) * 32;

  for (int half = 0; half < 2; ++half) {
    const int qt = half ? (31 - xb) : xb;
    const int qbase = qt * 32;
    const int qW = qbase + w * 16;
    const unsigned short* Qp = Qb + ((size_t)((b * NH + h) * SS + qW)) * 64;
    bf8v aQ0 = *(const bf8v*)(Qp + (size_t)lr * 64 + lg * 8);
    bf8v aQ1 = *(const bf8v*)(Qp + (size_t)lr * 64 + 32 + lg * 8);

    f4v o[4] = {{0,0,0,0},{0,0,0,0},{0,0,0,0},{0,0,0,0}};
    float lsumL[4] = {0.f, 0.f, 0.f, 0.f};

    for (int kvb = 0; kvb < qbase + 32; kvb += 64) {
      __syncthreads();
      const unsigned short* vp = Vp + (size_t)vd * SS + kvb + vso;
      const bf8v v0 = *(const bf8v*)(vp);
      const bf8v v1 = *(const bf8v*)(vp + 8);
      const bf8v v2 = *(const bf8v*)(vp + 16);
      const bf8v v3 = *(const bf8v*)(vp + 24);

      f4v sc[4] = {{0,0,0,0},{0,0,0,0},{0,0,0,0},{0,0,0,0}};
      __builtin_amdgcn_s_setprio(1);
#pragma unroll
      for (int c = 0; c < 4; ++c) {
        const unsigned short* kr = Kp + (size_t)(kvb + c * 16 + lr) * 64 + lg * 8;
        bf8v b0 = *(const bf8v*)(kr);
        bf8v b1 = *(const bf8v*)(kr + 32);
        sc[c] = __builtin_amdgcn_mfma_f32_16x16x32_bf16(aQ0, b0, sc[c], 0, 0, 0);
        sc[c] = __builtin_amdgcn_mfma_f32_16x16x32_bf16(aQ1, b1, sc[c], 0, 0, 0);
      }
      __builtin_amdgcn_s_setprio(0);

#pragma unroll
      for (int r = 0; r < 4; ++r) {
        const int qrow = qW + lg * 4 + r;
        float ps = 0.f;
        unsigned short pb[4];
#pragma unroll
        for (int c = 0; c < 4; ++c) {
          const float s = ((kvb + c * 16 + lr) > qrow) ? -INFINITY : sc[c][r];
          const float p = __expf(s);
          ps += p;
          pb[c] = f2b(p);
        }
        lsumL[r] += ps;
#pragma unroll
        for (int c = 0; c < 4; ++c) PL[w][lg * 4 + r][c * 16 + lr] = pb[c];
      }

      *(bf8v*)&VT[vd][vso]      = v0;
      *(bf8v*)&VT[vd][vso + 8]  = v1;
      *(bf8v*)&VT[vd][vso + 16] = v2;
      *(bf8v*)&VT[vd][vso + 24] = v3;

      __syncthreads();

      bf8v aP0 = *(const bf8v*)&PL[w][lr][lg * 8];
      bf8v aP1 = *(const bf8v*)&PL[w][lr][32 + lg * 8];
      __builtin_amdgcn_s_setprio(1);
#pragma unroll
      for (int n = 0; n < 4; ++n) {
        bf8v bV0 = *(const bf8v*)&VT[n * 16 + lr][lg * 8];
        bf8v bV1 = *(const bf8v*)&VT[n * 16 + lr][32 + lg * 8];
        o[n] = __builtin_amdgcn_mfma_f32_16x16x32_bf16(aP0, bV0, o[n], 0, 0, 0);
        o[n] = __builtin_amdgcn_mfma_f32_16x16x32_bf16(aP1, bV1, o[n], 0, 0, 0);
      }
      __builtin_amdgcn_s_setprio(0);
    }

#pragma unroll
    for (int r = 0; r < 4; ++r) {
      float ls = lsumL[r];
      ls += __shfl_xor(ls, 1);
      ls += __shfl_xor(ls, 2);
      ls += __shfl_xor(ls, 4);
      ls += __shfl_xor(ls, 8);
      const float inv = 1.0f / ls;
      const int row = qW + lg * 4 + r;
      unsigned short* dst = attn + (size_t)(b * SS + row) * HID + h * 64;
#pragma unroll
      for (int n = 0; n < 4; ++n) dst[n * 16 + lr] = f2b(o[n][r] * inv);
    }
  }
}

// ---------------------------------------------------------------------------
extern "C" void kernel_launch(void* const* d_in, const int* in_sizes, int n_in,
                              void* d_out, int out_size, void* d_ws, size_t ws_size,
                              hipStream_t stream) {
  const float* hidden = (const float*)d_in[0];
  const int*   pos    = (const int*)d_in[1];
  const float* Wq = (const float*)d_in[3];
  const float* Wk = (const float*)d_in[4];
  const float* Wv = (const float*)d_in[5];
  const float* Wo = (const float*)d_in[6];
  float* out = (float*)d_out;

  char* ws = (char*)d_ws;
  unsigned short* WqkvT = (unsigned short*)(ws);              // 12 MB  [3072][2048]
  unsigned short* WoT   = (unsigned short*)(ws + 12582912);   //  8 MB  [2048][2048]
  unsigned short* Xb    = (unsigned short*)(ws + 20971520);   //  8 MB  [M][2048]
  unsigned short* attnb = Xb;                                 // alias (Xb dead after gemm_qkv)
  unsigned short* Qb    = (unsigned short*)(ws + 29360128);   //  8 MB  [B][NH][S][64]
  unsigned short* Kb    = (unsigned short*)(ws + 37748736);   //  2 MB  [B][NKV][S][64]
  unsigned short* Vb    = (unsigned short*)(ws + 39845888);   //  2 MB  [B][NKV][S][64]
  unsigned short* Vt    = (unsigned short*)(ws + 41943040);   //  2 MB  [B*NKV][64][S]
  float2*         tab   = (float2*)(ws + 44040192);           // 512 KB [M][32]

  dim3 blk(256);

  prepAll<<<dim3(32, 32, 6), blk, 0, stream>>>(Wq, Wk, Wv, Wo, hidden, pos,
                                               WqkvT, WoT, Xb, tab);

  // QKV: 24 x 32 = 768 blocks = 3 blocks/CU exact
  gemm_qkv<<<dim3(NQKV / 128, M / 64), blk, 0, stream>>>(Xb, WqkvT, tab, Qb, Kb, Vb);

  vtrans<<<dim3(SS / 64, BB * NKV), blk, 0, stream>>>(Vb, Vt);

  attn_mfma<<<dim3(16, NH, BB), dim3(128), 0, stream>>>(Qb, Kb, Vt, attnb);

  // Wo: 16 x 32 = 512 blocks = 2 blocks/CU exact
  gemm_bf16<<<dim3(HID / 128, M / 64), blk, 0, stream>>>(attnb, WoT, out, HID);
}